// Round 7
// baseline (378.595 us; speedup 1.0000x reference)
//
#include <hip/hip_runtime.h>
#include <math.h>

#define NHEADS 8
#define NC 9
#define NHC 72
#define FIN 12
#define WPB 4           // waves per block in k_gat
#define ROWW 48         // words per node row: 4 pairs x 3 x 16B units = 192 B
#define MAXBUK 512      // supports N <= 131072 (bucket = dst >> 8)
#define TILE 4096       // edges per k_bucketA block
#define EXW 10          // LDS ex row stride (floats) -> 8B-aligned pair reads

__device__ __forceinline__ float lrelu(float v) { return v > 0.f ? v : 0.2f * v; }

// round-to-nearest-even bf16 pack of two floats into one uint (a=low, b=high)
__device__ __forceinline__ unsigned pack_bf16(float a, float b) {
    unsigned ua = __float_as_uint(a); ua += 0x7fffu + ((ua >> 16) & 1u);
    unsigned ub = __float_as_uint(b); ub += 0x7fffu + ((ub >> 16) & 1u);
    return (ua >> 16) | (ub & 0xffff0000u);
}
__device__ __forceinline__ float blo(unsigned w) { return __uint_as_float(w << 16); }
__device__ __forceinline__ float bhi(unsigned w) { return __uint_as_float(w & 0xffff0000u); }

// K1: per-node linear transform -> head-pair-packed bf16 rows; al_s/al_d f32 arrays.
// Fused tail: bucket histogram of dst (LDS-aggregated).
__global__ void __launch_bounds__(256) k_transform(
    const float* __restrict__ x, const float* __restrict__ W,
    const float* __restrict__ a_src, const float* __restrict__ a_dst,
    unsigned* __restrict__ hrow, float* __restrict__ als_arr, float* __restrict__ al_d,
    const int* __restrict__ dst, int* __restrict__ bucket_count,
    int N, int E, int nbuk)
{
    __shared__ float sW[FIN * NHC];
    __shared__ float sas[NHC];
    __shared__ float sad[NHC];
    __shared__ int bcnt[MAXBUK];
    int tid = threadIdx.x;
    for (int i = tid; i < FIN * NHC; i += blockDim.x) sW[i] = W[i];
    if (tid < NHC) { sas[tid] = a_src[tid]; sad[tid] = a_dst[tid]; }
    for (int i = tid; i < nbuk; i += blockDim.x) bcnt[i] = 0;
    __syncthreads();
    int n = blockIdx.x * blockDim.x + tid;
    if (n < N) {
        float xv[FIN];
        const float4* xp = reinterpret_cast<const float4*>(x + (size_t)n * FIN);
        float4 q0 = xp[0], q1 = xp[1], q2 = xp[2];
        xv[0] = q0.x; xv[1] = q0.y; xv[2] = q0.z; xv[3] = q0.w;
        xv[4] = q1.x; xv[5] = q1.y; xv[6] = q1.z; xv[7] = q1.w;
        xv[8] = q2.x; xv[9] = q2.y; xv[10] = q2.z; xv[11] = q2.w;

        float acc[NHC];
        #pragma unroll
        for (int j = 0; j < NHC; ++j) acc[j] = 0.f;
        #pragma unroll
        for (int k = 0; k < FIN; ++k) {
            float xk = xv[k];
            #pragma unroll
            for (int j = 0; j < NHC; ++j) acc[j] = fmaf(xk, sW[k * NHC + j], acc[j]);
        }

        // pack: pair p holds heads 2p,2p+1 as 18 consecutive cols -> 3 x 16B units
        uint4* rp = reinterpret_cast<uint4*>(hrow + (size_t)n * ROWW);
        #pragma unroll
        for (int pp = 0; pp < 4; ++pp) {
            const float* A = acc + pp * 18;
            uint4 u0, u1, u2;
            u0.x = pack_bf16(A[0],  A[1]);  u0.y = pack_bf16(A[2],  A[3]);
            u0.z = pack_bf16(A[4],  A[5]);  u0.w = pack_bf16(A[6],  A[7]);
            u1.x = pack_bf16(A[8],  A[9]);  u1.y = pack_bf16(A[10], A[11]);
            u1.z = pack_bf16(A[12], A[13]); u1.w = pack_bf16(A[14], A[15]);
            u2.x = pack_bf16(A[16], A[17]); u2.y = 0u; u2.z = 0u; u2.w = 0u;
            rp[pp * 3 + 0] = u0; rp[pp * 3 + 1] = u1; rp[pp * 3 + 2] = u2;
        }

        #pragma unroll
        for (int hh = 0; hh < NHEADS; ++hh) {
            float ss = 0.f, dd = 0.f;
            #pragma unroll
            for (int c = 0; c < NC; ++c) {
                ss = fmaf(acc[hh * NC + c], sas[hh * NC + c], ss);
                dd = fmaf(acc[hh * NC + c], sad[hh * NC + c], dd);
            }
            als_arr[(size_t)n * NHEADS + hh] = ss;
            al_d[(size_t)n * NHEADS + hh] = dd;
        }
    }
    // fused bucket histogram (LDS-aggregated)
    int stride = gridDim.x * blockDim.x;
    for (int i = blockIdx.x * blockDim.x + tid; i < E; i += stride)
        atomicAdd(&bcnt[dst[i] >> 8], 1);
    __syncthreads();
    for (int i = tid; i < nbuk; i += blockDim.x)
        if (bcnt[i]) atomicAdd(&bucket_count[i], bcnt[i]);
}

// K2: single-block scan of bucket counts -> bucket_base, gcur; rowptr[N]=E.
__global__ void __launch_bounds__(512) k_bscan(
    const int* __restrict__ bucket_count, int* __restrict__ bucket_base,
    int* __restrict__ gcur, int* __restrict__ rowptr, int nbuk, int N, int E)
{
    __shared__ int s[512];
    int t = threadIdx.x;
    int v = (t < nbuk) ? bucket_count[t] : 0;
    s[t] = v;
    __syncthreads();
    for (int off = 1; off < 512; off <<= 1) {
        int u = (t >= off) ? s[t - off] : 0;
        __syncthreads();
        s[t] += u;
        __syncthreads();
    }
    if (t < nbuk) {
        int ex = s[t] - v;
        bucket_base[t] = ex;
        gcur[t] = ex;
    }
    if (t == 0) { bucket_base[nbuk] = E; rowptr[N] = E; }
}

// K3: coarse scatter into buckets: packed (src | d_local<<24), 4B/edge.
__global__ void __launch_bounds__(256) k_bucketA(
    const int* __restrict__ src, const int* __restrict__ dst,
    int* __restrict__ gcur, unsigned* __restrict__ bpair, int E, int nbuk)
{
    __shared__ int cnt[MAXBUK];
    __shared__ int sbase[MAXBUK];
    int t = threadIdx.x;
    for (int i = t; i < nbuk; i += 256) cnt[i] = 0;
    __syncthreads();
    int base0 = blockIdx.x * TILE;
    int rk[16], bk[16];
    unsigned pk[16];
    #pragma unroll
    for (int j = 0; j < 16; ++j) {
        int i = base0 + j * 256 + t;          // coalesced
        if (i < E) {
            int d = dst[i];
            int sg = src[i];
            bk[j] = d >> 8;
            pk[j] = (unsigned)sg | ((unsigned)(d & 255) << 24);
            rk[j] = atomicAdd(&cnt[bk[j]], 1);
        } else bk[j] = -1;
    }
    __syncthreads();
    for (int b = t; b < nbuk; b += 256)
        if (cnt[b]) sbase[b] = atomicAdd(&gcur[b], cnt[b]);
    __syncthreads();
    #pragma unroll
    for (int j = 0; j < 16; ++j)
        if (bk[j] >= 0) bpair[sbase[bk[j]] + rk[j]] = pk[j];
}

// K4: one block per bucket: per-node counts -> rowptr, then fine scatter.
__global__ void __launch_bounds__(256) k_bucketB(
    const unsigned* __restrict__ bpair, const int* __restrict__ bucket_base,
    int* __restrict__ rowptr, int* __restrict__ sorted_src, int N)
{
    __shared__ int cnt[256];
    __shared__ int sc[256];
    int b = blockIdx.x;
    int t = threadIdx.x;
    int lo = bucket_base[b], hi = bucket_base[b + 1];
    cnt[t] = 0;
    __syncthreads();
    for (int i = lo + t; i < hi; i += 256)
        atomicAdd(&cnt[bpair[i] >> 24], 1);
    __syncthreads();
    int v = cnt[t];
    sc[t] = v;
    __syncthreads();
    for (int off = 1; off < 256; off <<= 1) {
        int u = (t >= off) ? sc[t - off] : 0;
        __syncthreads();
        sc[t] += u;
        __syncthreads();
    }
    int excl = sc[t] - v;
    int node = (b << 8) + t;
    if (node < N) rowptr[node] = lo + excl;
    __syncthreads();
    cnt[t] = lo + excl;                       // repurpose as absolute cursor
    __syncthreads();
    for (int i = lo + t; i < hi; i += 256) {
        unsigned w = bpair[i];
        int pos = atomicAdd(&cnt[w >> 24], 1);
        sorted_src[pos] = (int)(w & 0xFFFFFFu);
    }
}

// K5: one wave per dst node. Softmax: 8x8 (edge,head) lanes. Aggregate: 12
// lanes x 16B per edge, 5 edges/pass, head-pair packed rows, zero per-value
// boundary logic. Per-lane partials merged via LDS atomics.
__global__ void __launch_bounds__(256) k_gat(
    const int* __restrict__ rowptr, const int* __restrict__ sorted_src,
    const unsigned* __restrict__ hrow, const float* __restrict__ als_arr,
    const float* __restrict__ al_d, const float* __restrict__ bias,
    float* __restrict__ out, int N)
{
    __shared__ int   s_src[WPB][66];
    __shared__ float s_ex[WPB][65][EXW];
    __shared__ float s_red[WPB][104];    // 96 real slots + dummy
    __shared__ float s_den[WPB][8];
    __shared__ float s_v[WPB][NC];

    int wid  = threadIdx.x >> 6;
    int lane = threadIdx.x & 63;
    int n = blockIdx.x * WPB + wid;
    if (n >= N) return;                          // uniform per wave

    int base  = rowptr[n];
    int total = rowptr[n + 1] - base + 1;        // + implicit self-loop at total-1

    int g  = lane >> 3;                          // softmax: edge-slot group
    int hh = lane & 7;                           // softmax: head
    float ald_h = al_d[(size_t)n * NHEADS + hh];

    // aggregate-phase lane mapping: lane = e_loc*12 + unit (lanes 60-63 dummy)
    bool dummy = lane >= 60;
    int e_loc = dummy ? 0 : lane / 12;
    int unit  = dummy ? (lane - 60) : (lane - e_loc * 12);
    int p = unit / 3;
    int u = unit - p * 3;
    int slot_base = dummy ? 96 : p * 24 + u * 8;
    int row_boff = unit * 16;
    int ex_off = 2 * p;
    bool selF_B = (u == 2);                      // word0.lo uses exB only in unit2
    bool selR_A = (u == 0);                      // rest uses exA only in unit0

    // init (per-wave private regions)
    if (lane < EXW) s_ex[wid][64][lane] = 0.f;
    s_red[wid][lane] = 0.f;
    if (lane < 104 - 64) s_red[wid][64 + lane] = 0.f;

    float acc[8];
    #pragma unroll
    for (int j = 0; j < 8; ++j) acc[j] = 0.f;
    float den_part = 0.f;
    const char* hbase = reinterpret_cast<const char*>(hrow);

    for (int cb = 0; cb < total; cb += 64) {
        int rem = total - cb;
        int clen = rem < 64 ? rem : 64;
        // aggregate reads slots [0, padTo5) (plus pre-zeroed slot 64);
        // softmax must zero-fill EVERY slot < min(padTo5,64)  (R6 bug: it
        // only covered round8(clen) < round5(clen) for clen%40 in {6,7,22,...})
        int padTo5 = ((clen + 4) / 5) * 5;       // <= 65
        int cov    = padTo5 > 64 ? 64 : padTo5;
        int clenR8 = (cov + 7) & ~7;             // <= 64

        int j = cb + lane;
        int s = n;
        if (j < total - 1) s = sorted_src[base + j];
        s_src[wid][lane] = s;
        if (lane == 0) s_src[wid][64] = n;

        // softmax phase: lane (g,hh) -> edge slot k*8+g, head hh
        for (int k = 0; k * 8 < clenR8; ++k) {
            int lj = k * 8 + g;
            int sv = s_src[wid][lj];
            float als = als_arr[(size_t)sv * NHEADS + hh];
            float ex = 0.f;
            if (cb + lj < total) ex = __expf(lrelu(als + ald_h));
            s_ex[wid][lj][hh] = ex;
            den_part += ex;
        }

        // aggregate phase: 5 edges per pass, 16B/lane, guard-free
        for (int eb = 0; eb < padTo5; eb += 5) {
            int ee = eb + e_loc;
            int sv = s_src[wid][ee];
            unsigned boff = (unsigned)sv * 192u + (unsigned)row_boff;
            uint4 w4 = *reinterpret_cast<const uint4*>(hbase + boff);
            float exA = s_ex[wid][ee][ex_off];
            float exB = s_ex[wid][ee][ex_off + 1];
            float exF = selF_B ? exB : exA;
            float exR = selR_A ? exA : exB;
            acc[0] = fmaf(exF, blo(w4.x), acc[0]);
            acc[1] = fmaf(exR, bhi(w4.x), acc[1]);
            acc[2] = fmaf(exR, blo(w4.y), acc[2]);
            acc[3] = fmaf(exR, bhi(w4.y), acc[3]);
            acc[4] = fmaf(exR, blo(w4.z), acc[4]);
            acc[5] = fmaf(exR, bhi(w4.z), acc[5]);
            acc[6] = fmaf(exR, blo(w4.w), acc[6]);
            acc[7] = fmaf(exR, bhi(w4.w), acc[7]);
        }
    }

    // denominator: reduce over the 8 g-groups per head
    den_part += __shfl_xor(den_part, 8, 64);
    den_part += __shfl_xor(den_part, 16, 64);
    den_part += __shfl_xor(den_part, 32, 64);
    if (lane < 8) s_den[wid][lane] = 1.f / (den_part + 1e-16f);

    // merge per-lane partials: slot = p*24 + u*8 + j (cols 0..17 real per pair),
    // dummies -> 96+
    #pragma unroll
    for (int jj = 0; jj < 8; ++jj)
        atomicAdd(&s_red[wid][slot_base + jj], acc[jj]);

    if (lane < NC) {
        float v = 0.f;
        #pragma unroll
        for (int h = 0; h < NHEADS; ++h) {
            int pp = h >> 1, hi5 = h & 1;
            v = fmaf(s_red[wid][pp * 24 + hi5 * 9 + lane], s_den[wid][h], v);
        }
        v = v * (1.f / NHEADS) + bias[lane];
        s_v[wid][lane] = v;
        float mx = -INFINITY;
        #pragma unroll
        for (int c = 0; c < NC; ++c) mx = fmaxf(mx, s_v[wid][c]);
        float sum = 0.f;
        #pragma unroll
        for (int c = 0; c < NC; ++c) sum += __expf(s_v[wid][c] - mx);
        float lse = mx + __logf(sum);
        out[(size_t)n * NC + lane] = s_v[wid][lane] - lse;
    }
}

extern "C" void kernel_launch(void* const* d_in, const int* in_sizes, int n_in,
                              void* d_out, int out_size, void* d_ws, size_t ws_size,
                              hipStream_t stream)
{
    const float* x     = (const float*)d_in[0];
    const int*   ei    = (const int*)d_in[1];
    const float* W     = (const float*)d_in[2];
    const float* a_src = (const float*)d_in[3];
    const float* a_dst = (const float*)d_in[4];
    const float* bias  = (const float*)d_in[5];

    int N = in_sizes[0] / FIN;   // 100000
    int E = in_sizes[1] / 2;     // 1600000
    const int* src = ei;
    const int* dst = ei + E;
    int nbuk = (N + 255) >> 8;   // 391

    char* ws = (char*)d_ws;
    unsigned* hrow = (unsigned*)ws;     ws += (size_t)N * ROWW * sizeof(unsigned);
    float* als_arr = (float*)ws;        ws += (size_t)N * NHEADS * sizeof(float);
    float* al_d = (float*)ws;           ws += (size_t)N * NHEADS * sizeof(float);
    int* rowptr = (int*)ws;             ws += (size_t)(N + 1) * sizeof(int);
    int* bucket_count = (int*)ws;       ws += (size_t)(MAXBUK + 1) * sizeof(int);
    int* bucket_base  = (int*)ws;       ws += (size_t)(MAXBUK + 1) * sizeof(int);
    int* gcur = (int*)ws;               ws += (size_t)MAXBUK * sizeof(int);
    unsigned* bpair = (unsigned*)ws;    ws += (size_t)E * sizeof(unsigned);
    int* sorted_src = (int*)ws;         ws += (size_t)E * sizeof(int);

    hipMemsetAsync(bucket_count, 0, (size_t)(MAXBUK + 1) * sizeof(int), stream);

    int nb_n = (N + 255) / 256;
    int nb_a = (E + TILE - 1) / TILE;

    k_transform<<<nb_n, 256, 0, stream>>>(x, W, a_src, a_dst, hrow, als_arr, al_d,
                                          dst, bucket_count, N, E, nbuk);
    k_bscan<<<1, 512, 0, stream>>>(bucket_count, bucket_base, gcur, rowptr,
                                   nbuk, N, E);
    k_bucketA<<<nb_a, 256, 0, stream>>>(src, dst, gcur, bpair, E, nbuk);
    k_bucketB<<<nbuk, 256, 0, stream>>>(bpair, bucket_base, rowptr, sorted_src, N);

    int nb_g = (N + WPB - 1) / WPB;
    k_gat<<<nb_g, 256, 0, stream>>>(rowptr, sorted_src, hrow, als_arr, al_d, bias,
                                    (float*)d_out, N);
}

// Round 8
// 168.920 us; speedup vs baseline: 2.2413x; 2.2413x over previous
//
#include <hip/hip_runtime.h>
#include <math.h>

#define NHEADS 8
#define NC 9
#define NHC 72
#define FIN 12
#define WAVES_PER_BLOCK 4
#define ROWW 48         // words per node row: 36 (72 bf16) + 8 (al_s f32) + 4 pad = 192 B
#define ALS_OFF 36      // word offset of al_s within row
#define MAXBUK 512      // supports N <= 131072 (bucket = dst >> 8)
#define TILE 4096       // edges per k_bucketA block

__device__ __forceinline__ float lrelu(float v) { return v > 0.f ? v : 0.2f * v; }

// round-to-nearest-even bf16 pack of two floats into one uint (a=low, b=high)
__device__ __forceinline__ unsigned pack_bf16(float a, float b) {
    unsigned ua = __float_as_uint(a); ua += 0x7fffu + ((ua >> 16) & 1u);
    unsigned ub = __float_as_uint(b); ub += 0x7fffu + ((ub >> 16) & 1u);
    return (ua >> 16) | (ub & 0xffff0000u);
}

// K1: per-node linear transform -> packed bf16 row [h | al_s]; al_d separate.
// Fused tail: bucket histogram of dst (LDS-aggregated).
__global__ void __launch_bounds__(256) k_transform(
    const float* __restrict__ x, const float* __restrict__ W,
    const float* __restrict__ a_src, const float* __restrict__ a_dst,
    unsigned* __restrict__ hrow, float* __restrict__ al_d,
    const int* __restrict__ dst, int* __restrict__ bucket_count,
    int N, int E, int nbuk)
{
    __shared__ float sW[FIN * NHC];
    __shared__ float sas[NHC];
    __shared__ float sad[NHC];
    __shared__ int bcnt[MAXBUK];
    int tid = threadIdx.x;
    for (int i = tid; i < FIN * NHC; i += blockDim.x) sW[i] = W[i];
    if (tid < NHC) { sas[tid] = a_src[tid]; sad[tid] = a_dst[tid]; }
    for (int i = tid; i < nbuk; i += blockDim.x) bcnt[i] = 0;
    __syncthreads();
    int n = blockIdx.x * blockDim.x + tid;
    if (n < N) {
        float xv[FIN];
        const float4* xp = reinterpret_cast<const float4*>(x + (size_t)n * FIN);
        float4 q0 = xp[0], q1 = xp[1], q2 = xp[2];
        xv[0] = q0.x; xv[1] = q0.y; xv[2] = q0.z; xv[3] = q0.w;
        xv[4] = q1.x; xv[5] = q1.y; xv[6] = q1.z; xv[7] = q1.w;
        xv[8] = q2.x; xv[9] = q2.y; xv[10] = q2.z; xv[11] = q2.w;

        float acc[NHC];
        #pragma unroll
        for (int j = 0; j < NHC; ++j) acc[j] = 0.f;
        #pragma unroll
        for (int k = 0; k < FIN; ++k) {
            float xk = xv[k];
            #pragma unroll
            for (int j = 0; j < NHC; ++j) acc[j] = fmaf(xk, sW[k * NHC + j], acc[j]);
        }

        unsigned* rp = hrow + (size_t)n * ROWW;
        #pragma unroll
        for (int l = 0; l < NHC / 2; ++l)
            rp[l] = pack_bf16(acc[2 * l], acc[2 * l + 1]);

        float* rf = reinterpret_cast<float*>(rp);
        #pragma unroll
        for (int hh = 0; hh < NHEADS; ++hh) {
            float ss = 0.f, dd = 0.f;
            #pragma unroll
            for (int c = 0; c < NC; ++c) {
                ss = fmaf(acc[hh * NC + c], sas[hh * NC + c], ss);
                dd = fmaf(acc[hh * NC + c], sad[hh * NC + c], dd);
            }
            rf[ALS_OFF + hh] = ss;
            al_d[(size_t)n * NHEADS + hh] = dd;
        }
    }
    // fused bucket histogram (LDS-aggregated)
    int stride = gridDim.x * blockDim.x;
    for (int i = blockIdx.x * blockDim.x + tid; i < E; i += stride)
        atomicAdd(&bcnt[dst[i] >> 8], 1);
    __syncthreads();
    for (int i = tid; i < nbuk; i += blockDim.x)
        if (bcnt[i]) atomicAdd(&bucket_count[i], bcnt[i]);
}

// K2: single-block scan of bucket counts -> bucket_base, gcur; rowptr[N]=E.
__global__ void __launch_bounds__(512) k_bscan(
    const int* __restrict__ bucket_count, int* __restrict__ bucket_base,
    int* __restrict__ gcur, int* __restrict__ rowptr, int nbuk, int N, int E)
{
    __shared__ int s[512];
    int t = threadIdx.x;
    int v = (t < nbuk) ? bucket_count[t] : 0;
    s[t] = v;
    __syncthreads();
    for (int off = 1; off < 512; off <<= 1) {
        int u = (t >= off) ? s[t - off] : 0;
        __syncthreads();
        s[t] += u;
        __syncthreads();
    }
    if (t < nbuk) {
        int ex = s[t] - v;
        bucket_base[t] = ex;
        gcur[t] = ex;
    }
    if (t == 0) { bucket_base[nbuk] = E; rowptr[N] = E; }
}

// K3: coarse scatter into buckets: packed (src | d_local<<24), 4B/edge.
__global__ void __launch_bounds__(256) k_bucketA(
    const int* __restrict__ src, const int* __restrict__ dst,
    int* __restrict__ gcur, unsigned* __restrict__ bpair, int E, int nbuk)
{
    __shared__ int cnt[MAXBUK];
    __shared__ int sbase[MAXBUK];
    int t = threadIdx.x;
    for (int i = t; i < nbuk; i += 256) cnt[i] = 0;
    __syncthreads();
    int base0 = blockIdx.x * TILE;
    int rk[16], bk[16];
    unsigned pk[16];
    #pragma unroll
    for (int j = 0; j < 16; ++j) {
        int i = base0 + j * 256 + t;          // coalesced
        if (i < E) {
            int d = dst[i];
            int sg = src[i];
            bk[j] = d >> 8;
            pk[j] = (unsigned)sg | ((unsigned)(d & 255) << 24);
            rk[j] = atomicAdd(&cnt[bk[j]], 1);
        } else bk[j] = -1;
    }
    __syncthreads();
    for (int b = t; b < nbuk; b += 256)
        if (cnt[b]) sbase[b] = atomicAdd(&gcur[b], cnt[b]);
    __syncthreads();
    #pragma unroll
    for (int j = 0; j < 16; ++j)
        if (bk[j] >= 0) bpair[sbase[bk[j]] + rk[j]] = pk[j];
}

// K4: one block per bucket: per-node counts -> rowptr, then fine scatter.
// Stores row BYTE OFFSETS (src*192) so k_gat skips the multiply.
__global__ void __launch_bounds__(256) k_bucketB(
    const unsigned* __restrict__ bpair, const int* __restrict__ bucket_base,
    int* __restrict__ rowptr, int* __restrict__ sorted_off, int N)
{
    __shared__ int cnt[256];
    __shared__ int sc[256];
    int b = blockIdx.x;
    int t = threadIdx.x;
    int lo = bucket_base[b], hi = bucket_base[b + 1];
    cnt[t] = 0;
    __syncthreads();
    for (int i = lo + t; i < hi; i += 256)
        atomicAdd(&cnt[bpair[i] >> 24], 1);
    __syncthreads();
    int v = cnt[t];
    sc[t] = v;
    __syncthreads();
    for (int off = 1; off < 256; off <<= 1) {
        int u = (t >= off) ? sc[t - off] : 0;
        __syncthreads();
        sc[t] += u;
        __syncthreads();
    }
    int excl = sc[t] - v;
    int node = (b << 8) + t;
    if (node < N) rowptr[node] = lo + excl;
    __syncthreads();
    cnt[t] = lo + excl;                       // repurpose as absolute cursor
    __syncthreads();
    for (int i = lo + t; i < hi; i += 256) {
        unsigned w = bpair[i];
        int pos = atomicAdd(&cnt[w >> 24], 1);
        sorted_off[pos] = (int)((w & 0xFFFFFFu) * (ROWW * 4u));
    }
}

// K5: one wave per dst node: no-max segment softmax + bf16 gather-aggregate + finalize.
// (R5-proven structure: 36 lanes x 4B per edge, 64 independent loads/chunk.)
__global__ void __launch_bounds__(256) k_gat(
    const int* __restrict__ rowptr, const int* __restrict__ sorted_off,
    const unsigned* __restrict__ hrow, const float* __restrict__ al_d,
    const float* __restrict__ bias, float* __restrict__ out, int N)
{
    __shared__ int   s_off[WAVES_PER_BLOCK][64];     // row BYTE offsets
    __shared__ float s_ex[WAVES_PER_BLOCK][64][9];   // [edge][head], pad 8->9
    __shared__ float s_den[WAVES_PER_BLOCK][8];
    __shared__ float s_out[WAVES_PER_BLOCK][NHC];
    __shared__ float s_v[WAVES_PER_BLOCK][NC];

    int wid  = threadIdx.x >> 6;
    int lane = threadIdx.x & 63;
    int n = blockIdx.x * WAVES_PER_BLOCK + wid;
    if (n >= N) return;                         // uniform per wave

    int base  = rowptr[n];
    int total = rowptr[n + 1] - base + 1;       // + implicit self-loop at index total-1

    int g  = lane >> 3;                         // edge-slot group (softmax phase)
    int hh = lane & 7;                          // head (softmax phase)
    float ald_h = al_d[(size_t)n * NHEADS + hh];

    bool act36 = lane < NHC / 2;
    int widx4 = act36 ? lane * 4 : 0;           // payload word byte-offset within row
    int c0 = 2 * lane, c1 = 2 * lane + 1;
    int ha = act36 ? c0 / NC : 0;
    int hb = act36 ? c1 / NC : 0;
    float accA = 0.f, accB = 0.f;
    float den_part = 0.f;

    const char* hbase = reinterpret_cast<const char*>(hrow);
    int als_boff = (ALS_OFF + hh) * 4;          // byte offset of my head's al_s in a row
    int self_off = n * (ROWW * 4);

    for (int cb = 0; cb < total; cb += 64) {
        int rem = total - cb;
        int clen = rem < 64 ? rem : 64;
        int clenR = (clen + 3) & ~3;            // guard-free round-up (<=64)

        // fill row byte-offsets for this chunk (j >= total-1 -> self row; safe pad)
        int j = cb + lane;
        int off_l = self_off;
        if (j < total - 1) off_l = sorted_off[base + j];
        s_off[wid][lane] = off_l;

        // softmax phase: lane (g,hh) handles local edges lj = k*8+g for head hh
        for (int k = 0; k * 8 < clenR; ++k) {
            int lj = k * 8 + g;
            int off = s_off[wid][lj];
            float als = *reinterpret_cast<const float*>(hbase + off + als_boff);
            float ex = 0.f;
            if (cb + lj < total) ex = __expf(lrelu(als + ald_h));
            s_ex[wid][lj][hh] = ex;
            den_part += ex;
        }

        // aggregation phase: guard-free, unrolled by 4
        for (int e = 0; e < clenR; e += 4) {
            #pragma unroll
            for (int p = 0; p < 4; ++p) {
                int ee = e + p;
                int off = s_off[wid][ee];
                unsigned w = *reinterpret_cast<const unsigned*>(hbase + off + widx4);
                float fa = __uint_as_float(w << 16);
                float fb = __uint_as_float(w & 0xffff0000u);
                accA = fmaf(s_ex[wid][ee][ha], fa, accA);
                accB = fmaf(s_ex[wid][ee][hb], fb, accB);
            }
        }
    }

    // denominator: 3-shuffle reduce across the 8 lanes sharing each head
    den_part += __shfl_xor(den_part, 8, 64);
    den_part += __shfl_xor(den_part, 16, 64);
    den_part += __shfl_xor(den_part, 32, 64);
    if (lane < 8) s_den[wid][lane] = den_part;

    if (act36) {
        float ia = 1.f / (s_den[wid][ha] + 1e-16f);
        float ib = 1.f / (s_den[wid][hb] + 1e-16f);
        s_out[wid][c0] = accA * ia;
        s_out[wid][c1] = accB * ib;
    }

    if (lane < NC) {
        float v = 0.f;
        #pragma unroll
        for (int h = 0; h < NHEADS; ++h) v += s_out[wid][h * NC + lane];
        v = v * (1.f / NHEADS) + bias[lane];
        s_v[wid][lane] = v;
        float mx = -INFINITY;
        #pragma unroll
        for (int c = 0; c < NC; ++c) mx = fmaxf(mx, s_v[wid][c]);
        float sum = 0.f;
        #pragma unroll
        for (int c = 0; c < NC; ++c) sum += __expf(s_v[wid][c] - mx);
        float lse = mx + __logf(sum);
        out[(size_t)n * NC + lane] = s_v[wid][lane] - lse;
    }
}

extern "C" void kernel_launch(void* const* d_in, const int* in_sizes, int n_in,
                              void* d_out, int out_size, void* d_ws, size_t ws_size,
                              hipStream_t stream)
{
    const float* x     = (const float*)d_in[0];
    const int*   ei    = (const int*)d_in[1];
    const float* W     = (const float*)d_in[2];
    const float* a_src = (const float*)d_in[3];
    const float* a_dst = (const float*)d_in[4];
    const float* bias  = (const float*)d_in[5];

    int N = in_sizes[0] / FIN;   // 100000
    int E = in_sizes[1] / 2;     // 1600000
    const int* src = ei;
    const int* dst = ei + E;
    int nbuk = (N + 255) >> 8;   // 391

    char* ws = (char*)d_ws;
    unsigned* hrow = (unsigned*)ws;     ws += (size_t)N * ROWW * sizeof(unsigned);
    float* al_d = (float*)ws;           ws += (size_t)N * NHEADS * sizeof(float);
    int* rowptr = (int*)ws;             ws += (size_t)(N + 1) * sizeof(int);
    int* bucket_count = (int*)ws;       ws += (size_t)(MAXBUK + 1) * sizeof(int);
    int* bucket_base  = (int*)ws;       ws += (size_t)(MAXBUK + 1) * sizeof(int);
    int* gcur = (int*)ws;               ws += (size_t)MAXBUK * sizeof(int);
    unsigned* bpair = (unsigned*)ws;    ws += (size_t)E * sizeof(unsigned);
    int* sorted_off = (int*)ws;         ws += (size_t)E * sizeof(int);

    hipMemsetAsync(bucket_count, 0, (size_t)(MAXBUK + 1) * sizeof(int), stream);

    int nb_n = (N + 255) / 256;
    int nb_a = (E + TILE - 1) / TILE;

    k_transform<<<nb_n, 256, 0, stream>>>(x, W, a_src, a_dst, hrow, al_d,
                                          dst, bucket_count, N, E, nbuk);
    k_bscan<<<1, 512, 0, stream>>>(bucket_count, bucket_base, gcur, rowptr,
                                   nbuk, N, E);
    k_bucketA<<<nb_a, 256, 0, stream>>>(src, dst, gcur, bpair, E, nbuk);
    k_bucketB<<<nbuk, 256, 0, stream>>>(bpair, bucket_base, rowptr, sorted_off, N);

    int nb_g = (N + WAVES_PER_BLOCK - 1) / WAVES_PER_BLOCK;
    k_gat<<<nb_g, 256, 0, stream>>>(rowptr, sorted_off, hrow, al_d, bias,
                                    (float*)d_out, N);
}